// Round 1
// baseline (157.669 us; speedup 1.0000x reference)
//
#include <hip/hip_runtime.h>
#include <math.h>

#define LOG_2PI_F 1.8378770664093453f
#define EPS_F 1e-10f
#define B_SZ 32
#define C_SZ 32
#define V_SZ 16
#define CV 512        // C*V
#define PACK 8        // floats per packed (b,c,v) record
#define PER_LANE 8    // CV / 64

// Pack per-(b,c,v): [mu0*inv .. mu5*inv, inv, coef] where
// coef = log_pres - 6*log(safe_s) - 3*log(2pi), inv = 1/max(s, EPS)
__global__ void prep_kernel(const float* __restrict__ vote,
                            const float* __restrict__ scales,
                            const float* __restrict__ log_pres,
                            float* __restrict__ ws) {
    int i = blockIdx.x * blockDim.x + threadIdx.x;
    if (i >= B_SZ * CV) return;
    float s = fmaxf(scales[i], EPS_F);
    float inv = 1.0f / s;
    float coef = log_pres[i] - 6.0f * __logf(s) - 3.0f * LOG_2PI_F;
    const float* mu = vote + (size_t)i * 6;
    float4 lo, hi;
    lo.x = mu[0] * inv; lo.y = mu[1] * inv; lo.z = mu[2] * inv; lo.w = mu[3] * inv;
    hi.x = mu[4] * inv; hi.y = mu[5] * inv; hi.z = inv;        hi.w = coef;
    float4* o = (float4*)(ws + (size_t)i * PACK);
    o[0] = lo;
    o[1] = hi;
}

// One wave (64 lanes) per point. Each lane: 8 components -> 8 logits ->
// local (max, sum-exp) -> 64-lane butterfly LSE merge -> lane0 accumulates
// into per-block LDS segment sums -> global atomics.
__global__ __launch_bounds__(256) void point_kernel(const float* __restrict__ x,
                                                    const int* __restrict__ batch,
                                                    const float* __restrict__ ws,
                                                    float* __restrict__ out_pe,
                                                    int n_pts) {
    __shared__ float part[B_SZ];
    int tid = threadIdx.x;
    if (tid < B_SZ) part[tid] = 0.0f;
    __syncthreads();

    int wave = (int)((blockIdx.x * (unsigned)blockDim.x + tid) >> 6);
    int lane = tid & 63;

    if (wave < n_pts) {
        int b = batch[wave];
        const float* xp = x + (size_t)wave * 6;
        float x0 = xp[0], x1 = xp[1], x2 = xp[2], x3 = xp[3], x4 = xp[4], x5 = xp[5];
        const float* base = ws + (size_t)b * CV * PACK + (size_t)lane * PACK;

        float l[PER_LANE];
#pragma unroll
        for (int k = 0; k < PER_LANE; ++k) {
            const float4* p = (const float4*)(base + (size_t)k * 64 * PACK);
            float4 lo = p[0];
            float4 hi = p[1];
            float inv = hi.z;
            float z, acc;
            z = fmaf(x0, inv, -lo.x); acc = z * z;
            z = fmaf(x1, inv, -lo.y); acc = fmaf(z, z, acc);
            z = fmaf(x2, inv, -lo.z); acc = fmaf(z, z, acc);
            z = fmaf(x3, inv, -lo.w); acc = fmaf(z, z, acc);
            z = fmaf(x4, inv, -hi.x); acc = fmaf(z, z, acc);
            z = fmaf(x5, inv, -hi.y); acc = fmaf(z, z, acc);
            l[k] = fmaf(acc, -0.5f, hi.w);
        }

        float m = l[0];
#pragma unroll
        for (int k = 1; k < PER_LANE; ++k) m = fmaxf(m, l[k]);
        float ssum = 0.0f;
#pragma unroll
        for (int k = 0; k < PER_LANE; ++k) ssum += __expf(l[k] - m);

        // 64-lane butterfly logsumexp merge
#pragma unroll
        for (int off = 32; off >= 1; off >>= 1) {
            float mo = __shfl_xor(m, off, 64);
            float so = __shfl_xor(ssum, off, 64);
            float mn = fmaxf(m, mo);
            ssum = ssum * __expf(m - mn) + so * __expf(mo - mn);
            m = mn;
        }

        if (lane == 0) {
            float lp = m + __logf(ssum);
            atomicAdd(&part[b], lp);
        }
    }

    __syncthreads();
    if (tid < B_SZ) {
        float v = part[tid];
        if (v != 0.0f) atomicAdd(&out_pe[tid], v);
    }
}

// d_out[0] = mean(d_out[1..32])
__global__ void final_kernel(float* __restrict__ d_out) {
    int t = threadIdx.x;
    float v = (t < B_SZ) ? d_out[1 + t] : 0.0f;
#pragma unroll
    for (int off = 32; off >= 1; off >>= 1) v += __shfl_xor(v, off, 64);
    if (t == 0) d_out[0] = v * (1.0f / B_SZ);
}

extern "C" void kernel_launch(void* const* d_in, const int* in_sizes, int n_in,
                              void* d_out, int out_size, void* d_ws, size_t ws_size,
                              hipStream_t stream) {
    const float* x        = (const float*)d_in[0];
    const float* vote     = (const float*)d_in[1];
    const float* scales   = (const float*)d_in[2];
    const float* log_pres = (const float*)d_in[3];
    const int*   batch    = (const int*)d_in[4];
    float* out = (float*)d_out;
    float* ws  = (float*)d_ws;

    int n_pts = in_sizes[0] / 6;

    // out is re-poisoned to 0xAA before every call -> zero it (capture-legal)
    hipMemsetAsync(d_out, 0, (size_t)out_size * sizeof(float), stream);

    prep_kernel<<<(B_SZ * CV + 255) / 256, 256, 0, stream>>>(vote, scales, log_pres, ws);

    int total_threads = n_pts * 64;
    point_kernel<<<(total_threads + 255) / 256, 256, 0, stream>>>(x, batch, ws, out + 1, n_pts);

    final_kernel<<<1, 64, 0, stream>>>(out);
}

// Round 6
// 95.592 us; speedup vs baseline: 1.6494x; 1.6494x over previous
//
#include <hip/hip_runtime.h>
#include <math.h>

#define LOG_2PI_F 1.8378770664093453f
#define EPS_F 1e-10f
#define NB 32        // batches
#define CV 512       // components per batch (C*V)
#define G 8          // threads per point
#define PPB 32       // points per block (256 threads / G)
#define CHUNK 16
#define NCHUNK 4     // 64 comps/thread = 4 chunks of 16

// online-LSE merge of a chunk of CHUNK logits l[] into running (m, ssum)
#define CHUNK_MERGE()                                              \
    do {                                                           \
        float cm = l[0];                                           \
        _Pragma("unroll")                                          \
        for (int j = 1; j < CHUNK; ++j) cm = fmaxf(cm, l[j]);      \
        float mn = fmaxf(m, cm);                                   \
        ssum *= __expf(m - mn);                                    \
        float e0 = 0.0f, e1 = 0.0f;                                \
        _Pragma("unroll")                                          \
        for (int j = 0; j < CHUNK; j += 2) {                       \
            e0 += __expf(l[j] - mn);                               \
            e1 += __expf(l[j + 1] - mn);                           \
        }                                                          \
        ssum += e0 + e1;                                           \
        m = mn;                                                    \
    } while (0)

__global__ __launch_bounds__(256) void capsule_main(
    const float* __restrict__ x,
    const float* __restrict__ vote,
    const float* __restrict__ scales,
    const float* __restrict__ log_pres,
    const int* __restrict__ batch,
    float* __restrict__ out_pe,
    int n_pts)
{
    // packed records for the block's batch: [c*2+0] = mu0..3 * inv,
    // [c*2+1] = {mu4*inv, mu5*inv, inv, coef}
    __shared__ float4 rec[CV * 2];
    __shared__ float part[NB];

    const int tid = threadIdx.x;
    const int p0  = blockIdx.x * PPB;
    const int b0  = batch[p0];

    if (tid < NB) part[tid] = 0.0f;

    // stage packed params for batch b0 (2 comps per thread), fused prep
    for (int c = tid; c < CV; c += 256) {
        float s    = fmaxf(scales[b0 * CV + c], EPS_F);
        float inv  = 1.0f / s;
        float coef = log_pres[b0 * CV + c] - 6.0f * __logf(s) - 3.0f * LOG_2PI_F;
        const float* mu = vote + ((size_t)(b0 * CV + c)) * 6;
        float4 lo, hi;
        lo.x = mu[0] * inv; lo.y = mu[1] * inv; lo.z = mu[2] * inv; lo.w = mu[3] * inv;
        hi.x = mu[4] * inv; hi.y = mu[5] * inv; hi.z = inv;        hi.w = coef;
        rec[c * 2 + 0] = lo;
        rec[c * 2 + 1] = hi;
    }
    __syncthreads();

    const int pl = tid >> 3;   // point within block
    const int g  = tid & 7;    // comp-group within point
    const int p  = p0 + pl;
    const bool valid = (p < n_pts);

    int pb = b0;
    if (valid) {
        pb = batch[p];
        const float* xp = x + (size_t)p * 6;
        const float x0 = xp[0], x1 = xp[1], x2 = xp[2],
                    x3 = xp[3], x4 = xp[4], x5 = xp[5];

        float m = -1e30f, ssum = 0.0f;

        if (pb == b0) {
            // hot path: params from LDS. comp index interleaved: c = g + i*8
            // -> per-iteration the wave reads 8 consecutive 32B records
            //    (broadcast across the 8 point-groups), ~conflict-free.
            #pragma unroll
            for (int ch = 0; ch < NCHUNK; ++ch) {
                float l[CHUNK];
                #pragma unroll
                for (int j = 0; j < CHUNK; ++j) {
                    const int c = g + (ch * CHUNK + j) * 8;
                    float4 lo = rec[c * 2 + 0];
                    float4 hi = rec[c * 2 + 1];
                    float z, acc;
                    z = fmaf(x0, hi.z, -lo.x); acc = z * z;
                    z = fmaf(x1, hi.z, -lo.y); acc = fmaf(z, z, acc);
                    z = fmaf(x2, hi.z, -lo.z); acc = fmaf(z, z, acc);
                    z = fmaf(x3, hi.z, -lo.w); acc = fmaf(z, z, acc);
                    z = fmaf(x4, hi.z, -hi.x); acc = fmaf(z, z, acc);
                    z = fmaf(x5, hi.z, -hi.y); acc = fmaf(z, z, acc);
                    l[j] = fmaf(acc, -0.5f, hi.w);
                }
                CHUNK_MERGE();
            }
        } else {
            // rare boundary fallback: block staged a different batch; read raw
            for (int ch = 0; ch < NCHUNK; ++ch) {
                float l[CHUNK];
                for (int j = 0; j < CHUNK; ++j) {
                    const int c = g + (ch * CHUNK + j) * 8;
                    float s    = fmaxf(scales[pb * CV + c], EPS_F);
                    float inv  = 1.0f / s;
                    float coef = log_pres[pb * CV + c]
                                 - 6.0f * __logf(s) - 3.0f * LOG_2PI_F;
                    const float* mu = vote + ((size_t)(pb * CV + c)) * 6;
                    float z, acc;
                    z = (x0 - mu[0]) * inv; acc = z * z;
                    z = (x1 - mu[1]) * inv; acc = fmaf(z, z, acc);
                    z = (x2 - mu[2]) * inv; acc = fmaf(z, z, acc);
                    z = (x3 - mu[3]) * inv; acc = fmaf(z, z, acc);
                    z = (x4 - mu[4]) * inv; acc = fmaf(z, z, acc);
                    z = (x5 - mu[5]) * inv; acc = fmaf(z, z, acc);
                    l[j] = fmaf(acc, -0.5f, coef);
                }
                CHUNK_MERGE();
            }
        }

        // merge the 8 partial LSEs of this point (lanes g=0..7)
        #pragma unroll
        for (int off = 1; off <= 4; off <<= 1) {
            float mo = __shfl_xor(m, off);
            float so = __shfl_xor(ssum, off);
            float mn = fmaxf(m, mo);
            ssum = ssum * __expf(m - mn) + so * __expf(mo - mn);
            m = mn;
        }
        if (g == 0) {
            float lp = m + __logf(ssum);
            atomicAdd(&part[pb], lp);
        }
    }

    __syncthreads();
    if (tid < NB) {
        float v = part[tid];
        if (v != 0.0f) atomicAdd(&out_pe[tid], v);
    }
}

// d_out[0] = mean(d_out[1..32])
__global__ void final_kernel(float* __restrict__ d_out) {
    int t = threadIdx.x;
    float v = (t < NB) ? d_out[1 + t] : 0.0f;
#pragma unroll
    for (int off = 32; off >= 1; off >>= 1) v += __shfl_xor(v, off, 64);
    if (t == 0) d_out[0] = v * (1.0f / NB);
}

extern "C" void kernel_launch(void* const* d_in, const int* in_sizes, int n_in,
                              void* d_out, int out_size, void* d_ws, size_t ws_size,
                              hipStream_t stream) {
    const float* x        = (const float*)d_in[0];
    const float* vote     = (const float*)d_in[1];
    const float* scales   = (const float*)d_in[2];
    const float* log_pres = (const float*)d_in[3];
    const int*   batch    = (const int*)d_in[4];
    float* out = (float*)d_out;

    int n_pts = in_sizes[0] / 6;

    // out is re-poisoned to 0xAA before every timed call -> zero it (capture-legal)
    hipMemsetAsync(d_out, 0, (size_t)out_size * sizeof(float), stream);

    int n_blocks = (n_pts + PPB - 1) / PPB;
    capsule_main<<<n_blocks, 256, 0, stream>>>(x, vote, scales, log_pres, batch,
                                               out + 1, n_pts);

    final_kernel<<<1, 64, 0, stream>>>(out);
}